// Round 5
// baseline (207.767 us; speedup 1.0000x reference)
//
#include <hip/hip_runtime.h>
#include <hip/hip_bf16.h>

// Problem constants (B,T,C,H from reference)
#define BATCH 8
#define SEQ   2048
#define EMB   1024
#define HD    128

typedef __attribute__((ext_vector_type(8))) short bf16x8;  // MFMA A/B frag (4 VGPR)
typedef __attribute__((ext_vector_type(4))) float f32x4;   // MFMA C/D frag

__device__ __forceinline__ short f2bf(float f) {           // RNE
    union { float f; unsigned u; } v; v.f = f;
    unsigned r = v.u + 0x7fffu + ((v.u >> 16) & 1u);
    return (short)(r >> 16);
}

// async global->LDS 16B/lane copy (wave-uniform LDS base + lane*16, per-lane src)
__device__ __forceinline__ void glds16(const short* g, short* l) {
    __builtin_amdgcn_global_load_lds(
        (const __attribute__((address_space(1))) unsigned int*)g,
        (__attribute__((address_space(3))) unsigned int*)l, 16, 0, 0);
}

// ===========================================================================
// FRAGMENT-IMAGE LAYOUTS (R6-verified): every MFMA fragment = one contiguous
// 1KB region = one fully-coalesced 16B/lane load for the consuming wave.
// W image (nh 0=K,1=V; k-chunk kc): slot(kk,f,l,q) -> W[nh*128+f*16+l][kc*64+kk*32+q*8+e]
// K image (b, jt): slot(kc,js,l,q) -> K[js*16+l][kc*32+q*8+e]
// V image (b, jt): slot(jc,f,l,q)  -> V[jc*32+q*8+e][f*16+l]
// ===========================================================================

__global__ void prep_w(const float* __restrict__ Wk, const float* __restrict__ Wv,
                       short* __restrict__ Wimg, int* __restrict__ cnt) {
    if (blockIdx.x == 0 && threadIdx.x < 256) cnt[threadIdx.x] = 0;  // merge tickets
    int g  = blockIdx.x * 256 + threadIdx.x;   // 0..32767
    int q  = g & 3;
    int l  = (g >> 2) & 15;
    int f  = (g >> 6) & 7;
    int kk = (g >> 9) & 1;
    int kc = (g >> 10) & 15;
    int nh = (g >> 14) & 1;
    const float* src = (nh ? Wv : Wk) + (size_t)(f * 16 + l) * EMB + kc * 64 + kk * 32 + q * 8;
    float4 f0 = *(const float4*)src;
    float4 f1 = *(const float4*)(src + 4);
    bf16x8 v;
    v[0]=f2bf(f0.x); v[1]=f2bf(f0.y); v[2]=f2bf(f0.z); v[3]=f2bf(f0.w);
    v[4]=f2bf(f1.x); v[5]=f2bf(f1.y); v[6]=f2bf(f1.z); v[7]=f2bf(f1.w);
    *(bf16x8*)&Wimg[(size_t)g * 8] = v;
}

// ---------------------------------------------------------------------------
// proj_kernel v8 VERBATIM (R8/R9-verified ~30us; R11's M=32 restructure
// REGRESSED +5us -- do not retry): [K|V] = x @ [Wk|Wv]^T. One block per
// 64-row tile computes BOTH K and V (x read once); W B-frags load directly
// from the global W-image (contiguous 1KB/wave, L2-resident). LDS = A dbuf
// only. Grid 256 x 512thr.
// ---------------------------------------------------------------------------
__global__ __launch_bounds__(512, 2)
void proj_kernel(const float* __restrict__ x, const short* __restrict__ Wimg,
                 short* __restrict__ Kimg,    // [8][32] 16KB images
                 short* __restrict__ Vimg)    // [8][32] 16KB images
{
    __shared__ __align__(16) union {
        short A[2][64][72];          // 18.4 KB A staging dbuf (+8 pad rows)
        short ep[16384];             // 32 KB epilogue: [K image | V image]
    } sm;

    const int tid  = threadIdx.x;
    const int wave = tid >> 6;
    const int lane = tid & 63;
    const int quad = lane >> 4;
    const int l16  = lane & 15;
    const int nh   = wave >> 2;        // 0 = K half, 1 = V half
    const int fb   = (wave & 3) * 2;   // f-pair base within the half
    const int mt   = blockIdx.x;       // 0..255 (64-row tile)
    const int row0 = mt * 64;

    const int srow = tid >> 3, sseg = tid & 7;
    const float* xsrc = x + (size_t)(row0 + srow) * EMB + sseg * 8;
    const short* wsrc = Wimg + (size_t)nh * 131072;

    f32x4 acc[4][2];                   // [mf][f2]
#pragma unroll
    for (int a = 0; a < 4; ++a)
#pragma unroll
        for (int c = 0; c < 2; ++c) acc[a][c] = f32x4{0.f, 0.f, 0.f, 0.f};

    {   // prime chunk 0
        float4 a0 = *(const float4*)xsrc;
        float4 a1 = *(const float4*)(xsrc + 4);
        bf16x8 v;
        v[0]=f2bf(a0.x); v[1]=f2bf(a0.y); v[2]=f2bf(a0.z); v[3]=f2bf(a0.w);
        v[4]=f2bf(a1.x); v[5]=f2bf(a1.y); v[6]=f2bf(a1.z); v[7]=f2bf(a1.w);
        *(bf16x8*)&sm.A[0][srow][sseg * 8] = v;
    }
    __syncthreads();

    for (int kc = 0; kc < 16; ++kc) {
        const int cur = kc & 1;
        float4 a0, a1;
        if (kc < 15) {                 // next chunk's HBM loads fly first
            const float* nx = xsrc + (kc + 1) * 64;
            a0 = *(const float4*)nx;
            a1 = *(const float4*)(nx + 4);
        }
        // B frags straight from global W-image (each = contiguous 1KB/wave)
        const short* wc = wsrc + (size_t)kc * 8192;
        bf16x8 bfr[2][2];
#pragma unroll
        for (int kk = 0; kk < 2; ++kk)
#pragma unroll
            for (int f2 = 0; f2 < 2; ++f2)
                bfr[kk][f2] = *(const bf16x8*)&wc[(((kk * 8 + fb + f2) * 16 + l16) * 4 + quad) * 8];

#pragma unroll
        for (int kk = 0; kk < 2; ++kk)
#pragma unroll
            for (int mf = 0; mf < 4; ++mf) {
                bf16x8 af = *(const bf16x8*)&sm.A[cur][mf * 16 + l16][kk * 32 + quad * 8];
#pragma unroll
                for (int f2 = 0; f2 < 2; ++f2)
                    acc[mf][f2] = __builtin_amdgcn_mfma_f32_16x16x32_bf16(af, bfr[kk][f2], acc[mf][f2], 0, 0, 0);
            }

        if (kc < 15) {                 // stage next chunk
            bf16x8 v;
            v[0]=f2bf(a0.x); v[1]=f2bf(a0.y); v[2]=f2bf(a0.z); v[3]=f2bf(a0.w);
            v[4]=f2bf(a1.x); v[5]=f2bf(a1.y); v[6]=f2bf(a1.z); v[7]=f2bf(a1.w);
            *(bf16x8*)&sm.A[cur ^ 1][srow][sseg * 8] = v;
        }
        __syncthreads();
    }

    // ---- epilogue: scatter C into both output fragment images in LDS ----
#pragma unroll
    for (int mf = 0; mf < 4; ++mf)
#pragma unroll
        for (int f2 = 0; f2 < 2; ++f2)
#pragma unroll
            for (int r = 0; r < 4; ++r) {
                const int row = mf * 16 + quad * 4 + r;          // j within tile
                const int h   = (fb + f2) * 16 + l16;            // col within half
                int idx;
                if (nh == 0)
                    idx = ((((h >> 5) * 4 + (row >> 4)) * 16 + (row & 15)) * 4 + ((h >> 3) & 3)) * 8 + (h & 7);
                else
                    idx = 8192 + ((((row >> 5) * 8 + (h >> 4)) * 16 + (h & 15)) * 4 + ((row >> 3) & 3)) * 8 + (row & 7);
                sm.ep[idx] = f2bf(acc[mf][f2][r]);
            }
    __syncthreads();

    {   // copy out 32KB, unit-interleaved
#pragma unroll
        for (int i = 0; i < 4; ++i) {
            const int g = i * 512 + tid;       // 16B unit 0..2047
            short* dst = (g < 1024) ? (Kimg + (size_t)mt * 8192 + g * 8)
                                    : (Vimg + (size_t)mt * 8192 + (g - 1024) * 8);
            *(bf16x8*)dst = *(const bf16x8*)&sm.ep[g * 8];
        }
    }
}

// ---------------------------------------------------------------------------
// attn_kernel v11 (R14): v10 inner iteration VERBATIM + balanced schedule.
//
// POST-MORTEM v10 (42us): degree-4 sharing DID cut per-work cost (790 cy per
// q-tile-iter vs v8's 1090) but 1 block/CU with n=G+1 in [1,32] left the
// G=31 CU doing 128 q-tile-iters vs 66 average -> kernel time = 32 iters.
// "Imbalance is harmless" was WRONG: the kernel is latency-bound (MfmaUtil
// 7%), not CU-bandwidth-bound, so the heavy CU gains nothing from idling
// neighbors.
//
// v11 schedule (per batch, 32 blocks): heavy blocks idx<16 take group
// G=16+idx, jt in [0,17) -> 17 iters. Light blocks idx>=16 run their own
// group G_l=idx-16 fully (n_l iters) THEN the tail jt in [17,G_h+1) of
// heavy group G_h=47-idx -> exactly 16 iters. Every CU: 16-17 iters.
// Split groups (G>=17): both halves write additive partials (O,l -- this
// kernel never tracks a softmax max, so partials ADD) to a ws slot; arrival
// ticket via device-scope atomicAdd; ticket==1 arriver merges + stores out.
// Partners share an XCD (bid&7). Counters zeroed by prep_w (same stream).
// ---------------------------------------------------------------------------
#define LOG2E 1.4426950408889634f

__global__ __launch_bounds__(512, 2)
void attn_kernel(const short* __restrict__ Kimg,  // [8][32] images
                 const short* __restrict__ Vimg,  // [8][32] images
                 float* __restrict__ out,         // [B, T, H] fp32
                 float* __restrict__ pbase,       // 120 slots x 2 x 8448 floats
                 int* __restrict__ cnt)           // 256 arrival tickets
{
    __shared__ __align__(16) short kbuf[2][8192]; // 32 KB K tile dbuf
    __shared__ __align__(16) short vbuf[8192];    // 16 KB V tile
    __shared__ __align__(16) short ps[4][1024];   // per-q-tile swizzled P (16x64)
    __shared__ float lsum[8][16];                 // per-wave l partials
    __shared__ int sflag;

    const int tid  = threadIdx.x;
    const int wave = tid >> 6;
    const int lane = tid & 63;
    const int quad = lane >> 4;
    const int l16  = lane & 15;

    const int b    = blockIdx.x & 7;              // XCD-affinity (batch b -> XCD b)
    const int idx  = blockIdx.x >> 3;             // 0..31 within batch
    const int qsel = wave >> 1;                   // q-tile within group (0..3)
    const int p    = wave & 1;                    // js-half (S) / h-half (PV)

    const short* Kb = Kimg + (size_t)b * 32 * 8192;
    const short* Vb = Vimg + (size_t)b * 32 * 8192;
    const float coef = LOG2E * 0.03125f;          // log2(e)/sqrt(C), sqrt(1024)=32
    short* psq = ps[qsel];

    // One phase = v10's whole kernel over jt in [j0, j1) for group Gp.
    // mode: 0 = direct store, 1 = heavy partial (sub-slot 0), 2 = tail partial (sub-slot 1)
    auto run_phase = [&](int Gp, int j0, int j1, int mode) {
        const int qt = 4 * Gp + qsel;

        // Q fragments from the diagonal K-image (Q = K projection)
        bf16x8 qf[4];
        {
            const short* qi = Kb + (size_t)Gp * 8192;
#pragma unroll
            for (int kc = 0; kc < 4; ++kc)
                qf[kc] = *(const bf16x8*)&qi[(((kc * 4 + qsel) * 16 + l16) * 4 + quad) * 8];
        }

        f32x4 O[4];                               // h-half: 16q x 64h
#pragma unroll
        for (int f = 0; f < 4; ++f) O[f] = f32x4{0.f, 0.f, 0.f, 0.f};
        float lp[4] = {0.f, 0.f, 0.f, 0.f};

        {   // prologue: stage K tile j0 (wave w copies 1KB x 2: 2 glds)
            const short* sk = Kb + (size_t)j0 * 8192 + wave * 1024 + lane * 8;
#pragma unroll
            for (int i = 0; i < 2; ++i)
                glds16(sk + i * 512, &kbuf[0][wave * 1024 + i * 512]);
        }

        int cur = 0;
        for (int jt = j0; jt < j1; ++jt) {
            // K[jt] glds done (issued ~a full iter ago); barrier => all
            // segments visible AND all waves past prev-iter vbuf/ps/kbuf reads.
            asm volatile("s_waitcnt vmcnt(0)" ::: "memory");
            __builtin_amdgcn_s_barrier();

            {   // stage V[jt] (consumed at PV this iter -- oldest in flight)
                const short* sv = Vb + (size_t)jt * 8192 + wave * 1024 + lane * 8;
#pragma unroll
                for (int i = 0; i < 2; ++i)
                    glds16(sv + i * 512, &vbuf[wave * 1024 + i * 512]);
            }
            const bool more = (jt + 1 < j1);
            if (more) {   // prefetch K[jt+1] into the other slot
                const short* sk = Kb + (size_t)(jt + 1) * 8192 + wave * 1024 + lane * 8;
#pragma unroll
                for (int i = 0; i < 2; ++i)
                    glds16(sk + i * 512, &kbuf[cur ^ 1][wave * 1024 + i * 512]);
            }

            // ---- S = Q K^T for this wave's js-half (from LDS) ----
            const short* kt = kbuf[cur];
            f32x4 S[2];
            S[0] = f32x4{0.f, 0.f, 0.f, 0.f};
            S[1] = f32x4{0.f, 0.f, 0.f, 0.f};
#pragma unroll
            for (int kc = 0; kc < 4; ++kc)
#pragma unroll
                for (int j2 = 0; j2 < 2; ++j2) {
                    bf16x8 kf = *(const bf16x8*)&kt[((kc * 4 + p * 2 + j2) * 64 + l16 * 4 + quad) * 8];
                    S[j2] = __builtin_amdgcn_mfma_f32_16x16x32_bf16(qf[kc], kf, S[j2], 0, 0, 0);
                }

            // ---- P = exp2(S*coef), causal mask on diag tile; swizzled ps ----
            const bool diag = (jt == Gp);         // heavy split part never has it
#pragma unroll
            for (int j2 = 0; j2 < 2; ++j2) {
                const int js = p * 2 + j2;
                const int jj = jt * 64 + js * 16 + l16;
                const int cb = js * 2 + (l16 >> 3);
                const int e  = l16 & 7;
#pragma unroll
                for (int r = 0; r < 4; ++r) {
                    float vv = S[j2][r] * coef;
                    if (diag && (jj > qt * 16 + quad * 4 + r)) vv = -INFINITY;
                    float pe = exp2f(vv);         // exp2(-inf) = 0
                    lp[r] += pe;
                    const int i8 = quad * 4 + r;
                    psq[(i8 * 8 + (cb ^ (i8 & 7))) * 8 + e] = f2bf(pe);
                }
            }

            // V[jt] landed (my 2 oldest); K[jt+1] stays in flight; ps visible.
            if (more) asm volatile("s_waitcnt vmcnt(2) lgkmcnt(0)" ::: "memory");
            else      asm volatile("s_waitcnt vmcnt(0) lgkmcnt(0)" ::: "memory");
            __builtin_amdgcn_s_barrier();

            // ---- O += P V for this wave's h-half (pa from shared ps) ----
#pragma unroll
            for (int jc = 0; jc < 2; ++jc) {
                const int pblk = l16 * 8 + ((jc * 4 + quad) ^ (l16 & 7));
                bf16x8 pa = *(const bf16x8*)&psq[pblk * 8];
#pragma unroll
                for (int fo = 0; fo < 4; ++fo) {
                    bf16x8 vf = *(const bf16x8*)&vbuf[((jc * 8 + p * 4 + fo) * 64 + l16 * 4 + quad) * 8];
                    O[fo] = __builtin_amdgcn_mfma_f32_16x16x32_bf16(pa, vf, O[fo], 0, 0, 0);
                }
            }
            cur ^= 1;
        }

        // ---- l: reduce this wave's js-half partials across the row's lanes ----
#pragma unroll
        for (int r = 0; r < 4; ++r) {
            float s = lp[r];
            s += __shfl_xor(s, 1);
            s += __shfl_xor(s, 2);
            s += __shfl_xor(s, 4);
            s += __shfl_xor(s, 8);
            lp[r] = s;
        }
        __syncthreads();                 // prior phase's lsum readers done
        if (l16 == 0) {
#pragma unroll
            for (int r = 0; r < 4; ++r) lsum[wave][quad * 4 + r] = lp[r];
        }
        __syncthreads();

        float Lp[4];                     // pair (p=0 + p=1) l for my rows
#pragma unroll
        for (int r = 0; r < 4; ++r)
            Lp[r] = lsum[qsel * 2][quad * 4 + r] + lsum[qsel * 2 + 1][quad * 4 + r];

        if (mode == 0) {                 // ---- direct normalize + store ----
#pragma unroll
            for (int r = 0; r < 4; ++r) {
                const int row16 = quad * 4 + r;
                const float inv = 1.f / Lp[r];
                const int row   = qt * 16 + row16;
                float* dst = out + (size_t)(b * SEQ + row) * HD + p * 64 + l16;
#pragma unroll
                for (int fo = 0; fo < 4; ++fo)
                    dst[fo * 16] = O[fo][r] * inv;
            }
        } else {                         // ---- partial store + ticket merge ----
            float* slot = pbase + (size_t)(b * 15 + (Gp - 17)) * 16896;
            float* my   = slot + (mode == 1 ? 0 : 8448);
            float* oth  = slot + (mode == 1 ? 8448 : 0);
#pragma unroll
            for (int fo = 0; fo < 4; ++fo)
#pragma unroll
                for (int r = 0; r < 4; ++r)
                    my[(fo * 4 + r) * 512 + tid] = O[fo][r];
            if (p == 0 && l16 == 0) {
#pragma unroll
                for (int r = 0; r < 4; ++r)
                    my[8192 + qsel * 16 + quad * 4 + r] = Lp[r];
            }
            __threadfence();
            __syncthreads();
            if (tid == 0) sflag = atomicAdd(&cnt[b * 32 + Gp], 1);
            __syncthreads();
            if (sflag == 1) {            // I'm second: merge + store
                __threadfence();
#pragma unroll
                for (int r = 0; r < 4; ++r) {
                    const int row16 = quad * 4 + r;
                    const float L   = Lp[r] + oth[8192 + qsel * 16 + row16];
                    const float inv = 1.f / L;
                    const int row   = qt * 16 + row16;
                    float* dst = out + (size_t)(b * SEQ + row) * HD + p * 64 + l16;
#pragma unroll
                    for (int fo = 0; fo < 4; ++fo)
                        dst[fo * 16] = (O[fo][r] + oth[(fo * 4 + r) * 512 + tid]) * inv;
                }
            }
        }
    };

    if (idx < 16) {                      // heavy block: group 16+idx, first 17 tiles
        const int G = 16 + idx;
        run_phase(G, 0, 17, (G == 16) ? 0 : 1);
    } else {                             // light block: own group + heavy tail
        const int Gl = idx - 16;
        const int Gh = 47 - idx;
        run_phase(Gl, 0, Gl + 1, 0);
        if (Gh >= 17) run_phase(Gh, 17, Gh + 1, 2);
    }
}

extern "C" void kernel_launch(void* const* d_in, const int* in_sizes, int n_in,
                              void* d_out, int out_size, void* d_ws, size_t ws_size,
                              hipStream_t stream) {
    const float* x  = (const float*)d_in[0];
    const float* Wk = (const float*)d_in[1];
    // d_in[2] = Wq is UNUSED: reference uses the key projection for q (source bug)
    const float* Wv = (const float*)d_in[3];
    float* out = (float*)d_out;

    short* Wimg = (short*)d_ws;                          // 512 KB
    short* Kimg = Wimg + (size_t)262144;                 // 4 MB
    short* Vimg = Kimg + (size_t)BATCH * 32 * 8192;      // 4 MB
    float* pbase = (float*)(Vimg + (size_t)BATCH * 32 * 8192);  // 8.1 MB partials
    int*   cnt   = (int*)(pbase + (size_t)120 * 16896);  // 256 tickets

    prep_w<<<128, 256, 0, stream>>>(Wk, Wv, Wimg, cnt);
    proj_kernel<<<256, 512, 0, stream>>>(x, Wimg, Kimg, Vimg);
    attn_kernel<<<256, 512, 0, stream>>>(Kimg, Vimg, out, pbase, cnt);
}

// Round 6
// 149.178 us; speedup vs baseline: 1.3927x; 1.3927x over previous
//
#include <hip/hip_runtime.h>
#include <hip/hip_bf16.h>

// Problem constants (B,T,C,H from reference)
#define BATCH 8
#define SEQ   2048
#define EMB   1024
#define HD    128

typedef __attribute__((ext_vector_type(8))) short bf16x8;  // MFMA A/B frag (4 VGPR)
typedef __attribute__((ext_vector_type(4))) float f32x4;   // MFMA C/D frag

__device__ __forceinline__ short f2bf(float f) {           // RNE
    union { float f; unsigned u; } v; v.f = f;
    unsigned r = v.u + 0x7fffu + ((v.u >> 16) & 1u);
    return (short)(r >> 16);
}

// async global->LDS 16B/lane copy (wave-uniform LDS base + lane*16, per-lane src)
__device__ __forceinline__ void glds16(const short* g, short* l) {
    __builtin_amdgcn_global_load_lds(
        (const __attribute__((address_space(1))) unsigned int*)g,
        (__attribute__((address_space(3))) unsigned int*)l, 16, 0, 0);
}

// ===========================================================================
// FRAGMENT-IMAGE LAYOUTS (R6-verified): every MFMA fragment = one contiguous
// 1KB region = one fully-coalesced 16B/lane load for the consuming wave.
// W image (nh 0=K,1=V; k-chunk kc): slot(kk,f,l,q) -> W[nh*128+f*16+l][kc*64+kk*32+q*8+e]
// K image (b, jt): slot(kc,js,l,q) -> K[js*16+l][kc*32+q*8+e]
// V image (b, jt): slot(jc,f,l,q)  -> V[jc*32+q*8+e][f*16+l]
// ===========================================================================

__global__ void prep_w(const float* __restrict__ Wk, const float* __restrict__ Wv,
                       short* __restrict__ Wimg) {
    int g  = blockIdx.x * 256 + threadIdx.x;   // 0..32767
    int q  = g & 3;
    int l  = (g >> 2) & 15;
    int f  = (g >> 6) & 7;
    int kk = (g >> 9) & 1;
    int kc = (g >> 10) & 15;
    int nh = (g >> 14) & 1;
    const float* src = (nh ? Wv : Wk) + (size_t)(f * 16 + l) * EMB + kc * 64 + kk * 32 + q * 8;
    float4 f0 = *(const float4*)src;
    float4 f1 = *(const float4*)(src + 4);
    bf16x8 v;
    v[0]=f2bf(f0.x); v[1]=f2bf(f0.y); v[2]=f2bf(f0.z); v[3]=f2bf(f0.w);
    v[4]=f2bf(f1.x); v[5]=f2bf(f1.y); v[6]=f2bf(f1.z); v[7]=f2bf(f1.w);
    *(bf16x8*)&Wimg[(size_t)g * 8] = v;
}

// ---------------------------------------------------------------------------
// proj_kernel v8 VERBATIM (R8/R9-verified ~30us; R11's M=32 restructure
// REGRESSED +5us -- do not retry): [K|V] = x @ [Wk|Wv]^T. One block per
// 64-row tile computes BOTH K and V (x read once); W B-frags load directly
// from the global W-image (contiguous 1KB/wave, L2-resident). LDS = A dbuf
// only. Grid 256 x 512thr.
// ---------------------------------------------------------------------------
__global__ __launch_bounds__(512, 2)
void proj_kernel(const float* __restrict__ x, const short* __restrict__ Wimg,
                 short* __restrict__ Kimg,    // [8][32] 16KB images
                 short* __restrict__ Vimg)    // [8][32] 16KB images
{
    __shared__ __align__(16) union {
        short A[2][64][72];          // 18.4 KB A staging dbuf (+8 pad rows)
        short ep[16384];             // 32 KB epilogue: [K image | V image]
    } sm;

    const int tid  = threadIdx.x;
    const int wave = tid >> 6;
    const int lane = tid & 63;
    const int quad = lane >> 4;
    const int l16  = lane & 15;
    const int nh   = wave >> 2;        // 0 = K half, 1 = V half
    const int fb   = (wave & 3) * 2;   // f-pair base within the half
    const int mt   = blockIdx.x;       // 0..255 (64-row tile)
    const int row0 = mt * 64;

    const int srow = tid >> 3, sseg = tid & 7;
    const float* xsrc = x + (size_t)(row0 + srow) * EMB + sseg * 8;
    const short* wsrc = Wimg + (size_t)nh * 131072;

    f32x4 acc[4][2];                   // [mf][f2]
#pragma unroll
    for (int a = 0; a < 4; ++a)
#pragma unroll
        for (int c = 0; c < 2; ++c) acc[a][c] = f32x4{0.f, 0.f, 0.f, 0.f};

    {   // prime chunk 0
        float4 a0 = *(const float4*)xsrc;
        float4 a1 = *(const float4*)(xsrc + 4);
        bf16x8 v;
        v[0]=f2bf(a0.x); v[1]=f2bf(a0.y); v[2]=f2bf(a0.z); v[3]=f2bf(a0.w);
        v[4]=f2bf(a1.x); v[5]=f2bf(a1.y); v[6]=f2bf(a1.z); v[7]=f2bf(a1.w);
        *(bf16x8*)&sm.A[0][srow][sseg * 8] = v;
    }
    __syncthreads();

    for (int kc = 0; kc < 16; ++kc) {
        const int cur = kc & 1;
        float4 a0, a1;
        if (kc < 15) {                 // next chunk's HBM loads fly first
            const float* nx = xsrc + (kc + 1) * 64;
            a0 = *(const float4*)nx;
            a1 = *(const float4*)(nx + 4);
        }
        // B frags straight from global W-image (each = contiguous 1KB/wave)
        const short* wc = wsrc + (size_t)kc * 8192;
        bf16x8 bfr[2][2];
#pragma unroll
        for (int kk = 0; kk < 2; ++kk)
#pragma unroll
            for (int f2 = 0; f2 < 2; ++f2)
                bfr[kk][f2] = *(const bf16x8*)&wc[(((kk * 8 + fb + f2) * 16 + l16) * 4 + quad) * 8];

#pragma unroll
        for (int kk = 0; kk < 2; ++kk)
#pragma unroll
            for (int mf = 0; mf < 4; ++mf) {
                bf16x8 af = *(const bf16x8*)&sm.A[cur][mf * 16 + l16][kk * 32 + quad * 8];
#pragma unroll
                for (int f2 = 0; f2 < 2; ++f2)
                    acc[mf][f2] = __builtin_amdgcn_mfma_f32_16x16x32_bf16(af, bfr[kk][f2], acc[mf][f2], 0, 0, 0);
            }

        if (kc < 15) {                 // stage next chunk
            bf16x8 v;
            v[0]=f2bf(a0.x); v[1]=f2bf(a0.y); v[2]=f2bf(a0.z); v[3]=f2bf(a0.w);
            v[4]=f2bf(a1.x); v[5]=f2bf(a1.y); v[6]=f2bf(a1.z); v[7]=f2bf(a1.w);
            *(bf16x8*)&sm.A[cur ^ 1][srow][sseg * 8] = v;
        }
        __syncthreads();
    }

    // ---- epilogue: scatter C into both output fragment images in LDS ----
#pragma unroll
    for (int mf = 0; mf < 4; ++mf)
#pragma unroll
        for (int f2 = 0; f2 < 2; ++f2)
#pragma unroll
            for (int r = 0; r < 4; ++r) {
                const int row = mf * 16 + quad * 4 + r;          // j within tile
                const int h   = (fb + f2) * 16 + l16;            // col within half
                int idx;
                if (nh == 0)
                    idx = ((((h >> 5) * 4 + (row >> 4)) * 16 + (row & 15)) * 4 + ((h >> 3) & 3)) * 8 + (h & 7);
                else
                    idx = 8192 + ((((row >> 5) * 8 + (h >> 4)) * 16 + (h & 15)) * 4 + ((row >> 3) & 3)) * 8 + (row & 7);
                sm.ep[idx] = f2bf(acc[mf][f2][r]);
            }
    __syncthreads();

    {   // copy out 32KB, unit-interleaved
#pragma unroll
        for (int i = 0; i < 4; ++i) {
            const int g = i * 512 + tid;       // 16B unit 0..2047
            short* dst = (g < 1024) ? (Kimg + (size_t)mt * 8192 + g * 8)
                                    : (Vimg + (size_t)mt * 8192 + (g - 1024) * 8);
            *(bf16x8*)dst = *(const bf16x8*)&sm.ep[g * 8];
        }
    }
}

// ---------------------------------------------------------------------------
// attn_kernel v12 (R15): v8 pipeline VERBATIM + de-duplicated LDS reads.
//
// POST-MORTEM v11 (100us): the phase-lambda rebalance destroyed the verified
// inner-loop codegen (uniform 2.4x stall multiplier, cause not attributable
// from counters) -- REVERTED. v10 (42us) showed imbalance dominates 1-block/
// CU quad-sharing. v8 (~28us, best) is balanced (512 blocks, 2/CU, heavy+
// light pairing) and sits AT the LDS-read ceiling: per block-iter reads =
// kf 32KB + vf 32KB + pa 8KB = 72KB (+32KB glds writes), ~80B/cy demanded
// at 2 blk/CU vs ~85B/cy ds_read_b128 ceiling.
//
// v12 = v8 with ONE change: wave w owns js-QUARTER w (S) and h-QUARTER w
// (PV) for BOTH q-tiles of the pair (v8: wave (qsel,p) owned js/h-half p of
// ONE q-tile, so qsel-pairs read the same kf/vf twice). kf reads 8->4,
// vf 8->4 per wave (pa 2->4, small): LDS reads 72->48KB/block-iter (-33%).
// Same 16 MFMA/wave/iter, same glds/barrier/vmcnt pipeline, same ps swizzle
// (cb in {2w,2w+1}: disjoint slots per wave), same merge-free O store
// (h-quarters disjoint); l now sums 4 wave partials via lsum[4][2][16].
// ---------------------------------------------------------------------------
#define LOG2E 1.4426950408889634f

__global__ __launch_bounds__(256, 2)
void attn_kernel(const short* __restrict__ Kimg,  // [8][32] images
                 const short* __restrict__ Vimg,  // [8][32] images
                 float* __restrict__ out)         // [B, T, H] fp32
{
    __shared__ __align__(16) short kbuf[2][8192]; // 32 KB K tile dbuf
    __shared__ __align__(16) short vbuf[8192];    // 16 KB V tile
    __shared__ __align__(16) short ps[2][1024];   // per-q-tile swizzled P (16x64)
    __shared__ float lsum[4][2][16];              // per-wave, per-q-tile l partials

    const int tid  = threadIdx.x;
    const int w    = tid >> 6;                    // wave = js-quarter & h-quarter
    const int lane = tid & 63;
    const int quad = lane >> 4;
    const int l16  = lane & 15;

    const int b    = blockIdx.x & 7;              // XCD-affinity
    const int gg   = blockIdx.x >> 3;             // 0..63
    const int G    = (blockIdx.x < 256) ? (63 - gg) : (gg - 32); // heavy first
    const int n    = (G >> 1) + 1;                // identical for both q-tiles

    const short* Kb = Kimg + (size_t)b * 32 * 8192;
    const short* Vb = Vimg + (size_t)b * 32 * 8192;

    // Q fragments for BOTH q-tiles (2G, 2G+1) from the diagonal K-image
    // (Q = K projection). qt>>2 = G>>1 for both; jsq = (2G+qsel)&3.
    bf16x8 qf[2][4];
    {
        const short* qi = Kb + (size_t)(G >> 1) * 8192;
#pragma unroll
        for (int qsel = 0; qsel < 2; ++qsel) {
            const int jsq = (2 * G + qsel) & 3;
#pragma unroll
            for (int kc = 0; kc < 4; ++kc)
                qf[qsel][kc] = *(const bf16x8*)&qi[(((kc * 4 + jsq) * 16 + l16) * 4 + quad) * 8];
        }
    }

    f32x4 O[2][2];                                // [qsel][fo2]: 16q x 32h each qsel
#pragma unroll
    for (int a = 0; a < 2; ++a)
#pragma unroll
        for (int c = 0; c < 2; ++c) O[a][c] = f32x4{0.f, 0.f, 0.f, 0.f};
    float lp[2][4] = {{0.f,0.f,0.f,0.f},{0.f,0.f,0.f,0.f}};

    const float coef = LOG2E * 0.03125f;          // log2(e)/sqrt(C), sqrt(1024)=32

    {   // prologue: stage K tile 0 (wave w copies 4KB: 4 x 1KB glds)
        const short* sk = Kb + w * 2048 + lane * 8;
#pragma unroll
        for (int i = 0; i < 4; ++i)
            glds16(sk + i * 512, &kbuf[0][w * 2048 + i * 512]);
    }

    int cur = 0;
    for (int jt = 0; jt < n; ++jt) {
        // K[jt] glds done (issued ~a full iter ago); barrier => all segments
        // visible AND all waves past their previous-iter vbuf/ps/kbuf reads.
        asm volatile("s_waitcnt vmcnt(0)" ::: "memory");
        __builtin_amdgcn_s_barrier();

        {   // stage V[jt] (consumed at PV this iter -- oldest in flight)
            const short* sv = Vb + (size_t)jt * 8192 + w * 2048 + lane * 8;
#pragma unroll
            for (int i = 0; i < 4; ++i)
                glds16(sv + i * 512, &vbuf[w * 2048 + i * 512]);
        }
        const bool more = (jt + 1 < n);
        if (more) {   // prefetch K[jt+1] into the other slot (drained next top)
            const short* sk = Kb + (size_t)(jt + 1) * 8192 + w * 2048 + lane * 8;
#pragma unroll
            for (int i = 0; i < 4; ++i)
                glds16(sk + i * 512, &kbuf[cur ^ 1][w * 2048 + i * 512]);
        }

        // ---- S = Q K^T, js-quarter w, BOTH q-tiles (kf read once) ----
        const short* kt = kbuf[cur];
        bf16x8 kf[4];
#pragma unroll
        for (int kc = 0; kc < 4; ++kc)
            kf[kc] = *(const bf16x8*)&kt[((kc * 4 + w) * 64 + l16 * 4 + quad) * 8];

        f32x4 S[2];
        S[0] = f32x4{0.f, 0.f, 0.f, 0.f};
        S[1] = f32x4{0.f, 0.f, 0.f, 0.f};
#pragma unroll
        for (int kc = 0; kc < 4; ++kc)
#pragma unroll
            for (int qsel = 0; qsel < 2; ++qsel)
                S[qsel] = __builtin_amdgcn_mfma_f32_16x16x32_bf16(qf[qsel][kc], kf[kc], S[qsel], 0, 0, 0);

        // ---- P = exp2(S*coef), causal mask on diag tile; swizzled ps write ----
        const bool diag = (jt == n - 1);
        const int jj = jt * 64 + w * 16 + l16;
        const int cb = w * 2 + (l16 >> 3);
        const int e  = l16 & 7;
#pragma unroll
        for (int qsel = 0; qsel < 2; ++qsel) {
            const int qtq = 2 * G + qsel;
            short* psq = ps[qsel];
#pragma unroll
            for (int r = 0; r < 4; ++r) {
                float vv = S[qsel][r] * coef;
                if (diag && (jj > qtq * 16 + quad * 4 + r)) vv = -INFINITY;
                float pe = exp2f(vv);             // exp2(-inf) = 0
                lp[qsel][r] += pe;
                const int i8 = quad * 4 + r;
                psq[(i8 * 8 + (cb ^ (i8 & 7))) * 8 + e] = f2bf(pe);
            }
        }

        // V[jt] landed (my 4 oldest); K[jt+1] stays in flight; ps visible.
        if (more) asm volatile("s_waitcnt vmcnt(4) lgkmcnt(0)" ::: "memory");
        else      asm volatile("s_waitcnt vmcnt(0) lgkmcnt(0)" ::: "memory");
        __builtin_amdgcn_s_barrier();

        // ---- O += P V, h-quarter w, BOTH q-tiles (vf read once) ----
#pragma unroll
        for (int jc = 0; jc < 2; ++jc) {
            bf16x8 vf0 = *(const bf16x8*)&vbuf[((jc * 8 + w * 2 + 0) * 64 + l16 * 4 + quad) * 8];
            bf16x8 vf1 = *(const bf16x8*)&vbuf[((jc * 8 + w * 2 + 1) * 64 + l16 * 4 + quad) * 8];
#pragma unroll
            for (int qsel = 0; qsel < 2; ++qsel) {
                const int pblk = l16 * 8 + ((jc * 4 + quad) ^ (l16 & 7));
                bf16x8 pa = *(const bf16x8*)&ps[qsel][pblk * 8];
                O[qsel][0] = __builtin_amdgcn_mfma_f32_16x16x32_bf16(pa, vf0, O[qsel][0], 0, 0, 0);
                O[qsel][1] = __builtin_amdgcn_mfma_f32_16x16x32_bf16(pa, vf1, O[qsel][1], 0, 0, 0);
            }
        }
        cur ^= 1;
    }

    // ---- l: reduce each js-quarter partial across the row's 16 lanes ----
#pragma unroll
    for (int qsel = 0; qsel < 2; ++qsel)
#pragma unroll
        for (int r = 0; r < 4; ++r) {
            float s = lp[qsel][r];
            s += __shfl_xor(s, 1);
            s += __shfl_xor(s, 2);
            s += __shfl_xor(s, 4);
            s += __shfl_xor(s, 8);
            lp[qsel][r] = s;
        }
    if (l16 == 0) {
#pragma unroll
        for (int qsel = 0; qsel < 2; ++qsel)
#pragma unroll
            for (int r = 0; r < 4; ++r) lsum[w][qsel][quad * 4 + r] = lp[qsel][r];
    }
    __syncthreads();

    // ---- store: wave w owns h-quarter w of both q-tiles; no O merge ----
#pragma unroll
    for (int qsel = 0; qsel < 2; ++qsel) {
        const int qtq = 2 * G + qsel;
#pragma unroll
        for (int r = 0; r < 4; ++r) {
            const int row16 = quad * 4 + r;
            const float L = lsum[0][qsel][row16] + lsum[1][qsel][row16]
                          + lsum[2][qsel][row16] + lsum[3][qsel][row16];
            const float inv = 1.f / L;
            const int row   = qtq * 16 + row16;
            float* dst = out + (size_t)(b * SEQ + row) * HD + w * 32 + l16;
            dst[0]  = O[qsel][0][r] * inv;
            dst[16] = O[qsel][1][r] * inv;
        }
    }
}

extern "C" void kernel_launch(void* const* d_in, const int* in_sizes, int n_in,
                              void* d_out, int out_size, void* d_ws, size_t ws_size,
                              hipStream_t stream) {
    const float* x  = (const float*)d_in[0];
    const float* Wk = (const float*)d_in[1];
    // d_in[2] = Wq is UNUSED: reference uses the key projection for q (source bug)
    const float* Wv = (const float*)d_in[3];
    float* out = (float*)d_out;

    short* Wimg = (short*)d_ws;                          // 512 KB
    short* Kimg = Wimg + (size_t)262144;                 // 4 MB
    short* Vimg = Kimg + (size_t)BATCH * 32 * 8192;      // 4 MB

    prep_w<<<128, 256, 0, stream>>>(Wk, Wv, Wimg);
    proj_kernel<<<256, 512, 0, stream>>>(x, Wimg, Kimg, Vimg);
    attn_kernel<<<512, 256, 0, stream>>>(Kimg, Vimg, out);
}